// Round 4
// baseline (519.894 us; speedup 1.0000x reference)
//
#include <hip/hip_runtime.h>

// cyclicLoss: out = mean((input-target)^2) + 0.1*sqrt( sum_{i<(N-1)*T} (input[i]-input[i+T])^2 )
// fp32, n = N*T = 2048*8192 = 16.8M elements (64 MB each array).
//
// R3 design: one-shot, zero loop-carried deps, minimal registers.
//   - Each thread: exactly 2 independent float4 triples (a,b,c) -> 6 dwordx4
//     loads issued back-to-back. 32-bit indices (n4 < 2^22). ~45 VGPRs ->
//     compiler can keep all 6 loads in flight (R2's U=4/64-bit variant got
//     squeezed to VGPR=32 and serialized).
//   - grid*BLOCK*2 == n/4 exactly for the bench shape; grid-stride outer loop
//     retained for generality (0 extra iterations here).
//   - Branch-free shifted load: clamped index + cndmask accumulate.
//   - Fused last-block ticket finalize (single dispatch + 4B memset).

#define LAMDA 0.1
#define BLOCK 256

__global__ __launch_bounds__(BLOCK) void cyclic_fused_kernel(
    const float4* __restrict__ in4,
    const float4* __restrict__ tg4,
    const int* __restrict__ pT,
    const int* __restrict__ pN,
    long long n,
    double* __restrict__ m_part,
    double* __restrict__ d_part,
    unsigned int* __restrict__ counter,
    float* __restrict__ out)
{
    const int T = pT[0];
    const int N = pN[0];
    const int n4 = (int)(n >> 2);
    const int t4 = T >> 2;
    const long long limit = (long long)(N - 1) * (long long)T;
    const int limit4 = (int)(limit >> 2);

    float mse_acc = 0.0f;
    float dif_acc = 0.0f;

    // tile = 2*BLOCK contiguous float4s per block per iteration
    const int tile = 2 * BLOCK;
    const int gstride = (int)gridDim.x * tile;

    for (int base = (int)blockIdx.x * tile + (int)threadIdx.x;
         base + BLOCK < n4 + 1; base += gstride) {
        const int i0 = base;
        const int i1 = base + BLOCK;
        // clamped shifted indices — always legal, no branch between loads
        const int j0 = (i0 < limit4) ? (i0 + t4) : i0;
        const int j1 = (i1 < limit4) ? (i1 + t4) : i1;

        // six independent loads, issued back-to-back
        float4 a0 = in4[i0];
        float4 a1 = in4[i1];
        float4 b0 = tg4[i0];
        float4 b1 = tg4[i1];
        float4 c0 = in4[j0];
        float4 c1 = in4[j1];

        float e0 = a0.x - b0.x, e1 = a0.y - b0.y, e2 = a0.z - b0.z, e3 = a0.w - b0.w;
        mse_acc += e0 * e0 + e1 * e1 + e2 * e2 + e3 * e3;
        e0 = a1.x - b1.x; e1 = a1.y - b1.y; e2 = a1.z - b1.z; e3 = a1.w - b1.w;
        mse_acc += e0 * e0 + e1 * e1 + e2 * e2 + e3 * e3;

        float d0 = a0.x - c0.x, d1 = a0.y - c0.y, d2 = a0.z - c0.z, d3 = a0.w - c0.w;
        float dd0 = d0 * d0 + d1 * d1 + d2 * d2 + d3 * d3;
        dif_acc += (i0 < limit4) ? dd0 : 0.0f;
        d0 = a1.x - c1.x; d1 = a1.y - c1.y; d2 = a1.z - c1.z; d3 = a1.w - c1.w;
        float dd1 = d0 * d0 + d1 * d1 + d2 * d2 + d3 * d3;
        dif_acc += (i1 < limit4) ? dd1 : 0.0f;
    }

    // ---- generic remainders (0 iterations for the bench shape) ----
    {
        const int gtid = (int)blockIdx.x * BLOCK + (int)threadIdx.x;
        const int nth = (int)gridDim.x * BLOCK;
        // float4s not covered by full tiles
        const int covered = (n4 / tile) * tile;
        for (int i = covered + gtid; i < n4; i += nth) {
            float4 a = in4[i];
            float4 b = tg4[i];
            float e0 = a.x - b.x, e1 = a.y - b.y, e2 = a.z - b.z, e3 = a.w - b.w;
            mse_acc += e0 * e0 + e1 * e1 + e2 * e2 + e3 * e3;
            if (i < limit4) {
                float4 c = in4[i + t4];
                float d0 = a.x - c.x, d1 = a.y - c.y, d2 = a.z - c.z, d3 = a.w - c.w;
                dif_acc += d0 * d0 + d1 * d1 + d2 * d2 + d3 * d3;
            }
        }
        const float* in = (const float*)in4;
        const float* tg = (const float*)tg4;
        long long idx = ((long long)n4 << 2) + gtid;
        if (idx < n) {
            float e = in[idx] - tg[idx];
            mse_acc += e * e;
        }
        long long didx = ((long long)limit4 << 2) + gtid;
        if (didx < limit) {
            float d = in[didx] - in[didx + T];
            dif_acc += d * d;
        }
    }

    // ---- block reduction: wave-64 shuffle, then LDS across 4 waves ----
    #pragma unroll
    for (int off = 32; off > 0; off >>= 1) {
        mse_acc += __shfl_down(mse_acc, off, 64);
        dif_acc += __shfl_down(dif_acc, off, 64);
    }
    __shared__ float s_m[4], s_d[4];
    const int wave = threadIdx.x >> 6;
    if ((threadIdx.x & 63) == 0) { s_m[wave] = mse_acc; s_d[wave] = dif_acc; }
    __syncthreads();

    __shared__ bool isLast;
    if (threadIdx.x == 0) {
        double m = (double)s_m[0] + (double)s_m[1] + (double)s_m[2] + (double)s_m[3];
        double d = (double)s_d[0] + (double)s_d[1] + (double)s_d[2] + (double)s_d[3];
        m_part[blockIdx.x] = m;
        d_part[blockIdx.x] = d;
        __threadfence();
        unsigned int old = atomicAdd(counter, 1u);
        isLast = (old == gridDim.x - 1);
    }
    __syncthreads();

    // ---- last block finalizes ----
    if (isLast) {
        __threadfence();
        double m = 0.0, d = 0.0;
        for (int i = threadIdx.x; i < (int)gridDim.x; i += BLOCK) {
            m += m_part[i];
            d += d_part[i];
        }
        #pragma unroll
        for (int off = 32; off > 0; off >>= 1) {
            m += __shfl_down(m, off, 64);
            d += __shfl_down(d, off, 64);
        }
        __shared__ double f_m[4], f_d[4];
        if ((threadIdx.x & 63) == 0) { f_m[wave] = m; f_d[wave] = d; }
        __syncthreads();
        if (threadIdx.x == 0) {
            double mt = f_m[0] + f_m[1] + f_m[2] + f_m[3];
            double dt = f_d[0] + f_d[1] + f_d[2] + f_d[3];
            double mse = mt / (double)n;
            double nom = (N != 1) ? (LAMDA * sqrt(dt)) : 0.0;
            out[0] = (float)(mse + nom);
        }
    }
}

extern "C" void kernel_launch(void* const* d_in, const int* in_sizes, int n_in,
                              void* d_out, int out_size, void* d_ws, size_t ws_size,
                              hipStream_t stream) {
    const float* input  = (const float*)d_in[0];
    const float* target = (const float*)d_in[1];
    const int*   pT     = (const int*)d_in[2];
    const int*   pN     = (const int*)d_in[3];
    float* out = (float*)d_out;

    const long long n = (long long)in_sizes[0];
    const long long n4 = n >> 2;

    // one tile (2*BLOCK float4s) per block: grid covers n4 exactly for the
    // bench shape (4,194,304 / 512 = 8192)
    long long g = (n4 + 2 * BLOCK - 1) / (2 * BLOCK);
    int grid = (int)((g < 1) ? 1 : ((g > 8192) ? 8192 : g));

    double* m_part = (double*)d_ws;
    double* d_part = m_part + grid;
    unsigned int* counter = (unsigned int*)(d_part + grid);

    hipMemsetAsync(counter, 0, sizeof(unsigned int), stream);

    cyclic_fused_kernel<<<grid, BLOCK, 0, stream>>>(
        (const float4*)input, (const float4*)target, pT, pN, n,
        m_part, d_part, counter, out);
}

// Round 5
// 176.179 us; speedup vs baseline: 2.9509x; 2.9509x over previous
//
#include <hip/hip_runtime.h>

// cyclicLoss: out = mean((input-target)^2) + 0.1*sqrt( sum_{i<(N-1)*T} (input[i]-input[i+T])^2 )
// fp32, n = N*T = 2048*8192 = 16.8M elements (64 MB each array).
//
// R4 = R0 skeleton (best: 75us) + two targeted fixes:
//   - NO per-block __threadfence / ticket atomic (R1-R3 showed ~45ns/block
//     serialization + L2 pollution, scaling with grid). Two dispatches again.
//   - Region-split loops: [0,limit4) loads a,b,c unconditionally;
//     [limit4,n4) loads a,b only -> no per-element branch, one wait round.
//   - Unroll x2 with all 6 loads grouped; __launch_bounds__(256,4) permits
//     ~128 VGPR so the compiler can actually keep them in flight
//     (R0's VGPR=12 forced 2 serialized wait-rounds per element).

#define LAMDA 0.1
#define BLOCK 256
#define GRID 2048

__global__ __launch_bounds__(BLOCK, 4) void cyclic_reduce_kernel(
    const float4* __restrict__ in4,
    const float4* __restrict__ tg4,
    const int* __restrict__ pT,
    const int* __restrict__ pN,
    long long n,
    double* __restrict__ ws)      // ws[0]=mse sum, ws[1]=diff sum
{
    const int T = pT[0];
    const int N = pN[0];
    const int n4 = (int)(n >> 2);
    const int t4 = T >> 2;
    const long long limit = (N > 1) ? (long long)(N - 1) * (long long)T : 0;
    const int limit4 = (int)(limit >> 2);

    float mse_acc = 0.0f;
    float dif_acc = 0.0f;

    const int nth  = (int)gridDim.x * BLOCK;
    const int gtid = (int)blockIdx.x * BLOCK + (int)threadIdx.x;

    // ---- region 1: [0, limit4) — a, b, c all unconditional ----
    int i = gtid;
    for (; i + nth < limit4; i += 2 * nth) {
        const int i1 = i + nth;
        // six loads, grouped, no branches between them
        float4 a0 = in4[i];
        float4 c0 = in4[i + t4];
        float4 b0 = tg4[i];
        float4 a1 = in4[i1];
        float4 c1 = in4[i1 + t4];
        float4 b1 = tg4[i1];

        float e0 = a0.x - b0.x, e1 = a0.y - b0.y, e2 = a0.z - b0.z, e3 = a0.w - b0.w;
        mse_acc += e0 * e0 + e1 * e1 + e2 * e2 + e3 * e3;
        float d0 = a0.x - c0.x, d1 = a0.y - c0.y, d2 = a0.z - c0.z, d3 = a0.w - c0.w;
        dif_acc += d0 * d0 + d1 * d1 + d2 * d2 + d3 * d3;

        e0 = a1.x - b1.x; e1 = a1.y - b1.y; e2 = a1.z - b1.z; e3 = a1.w - b1.w;
        mse_acc += e0 * e0 + e1 * e1 + e2 * e2 + e3 * e3;
        d0 = a1.x - c1.x; d1 = a1.y - c1.y; d2 = a1.z - c1.z; d3 = a1.w - c1.w;
        dif_acc += d0 * d0 + d1 * d1 + d2 * d2 + d3 * d3;
    }
    for (; i < limit4; i += nth) {
        float4 a = in4[i];
        float4 c = in4[i + t4];
        float4 b = tg4[i];
        float e0 = a.x - b.x, e1 = a.y - b.y, e2 = a.z - b.z, e3 = a.w - b.w;
        mse_acc += e0 * e0 + e1 * e1 + e2 * e2 + e3 * e3;
        float d0 = a.x - c.x, d1 = a.y - c.y, d2 = a.z - c.z, d3 = a.w - c.w;
        dif_acc += d0 * d0 + d1 * d1 + d2 * d2 + d3 * d3;
    }

    // ---- region 2: [limit4, n4) — mse only ----
    for (int k = limit4 + gtid; k < n4; k += nth) {
        float4 a = in4[k];
        float4 b = tg4[k];
        float e0 = a.x - b.x, e1 = a.y - b.y, e2 = a.z - b.z, e3 = a.w - b.w;
        mse_acc += e0 * e0 + e1 * e1 + e2 * e2 + e3 * e3;
    }

    // ---- scalar tails (none for the bench shape; kept generic) ----
    {
        const float* in = (const float*)in4;
        const float* tg = (const float*)tg4;
        long long idx = ((long long)n4 << 2) + gtid;
        if (idx < n) {
            float e = in[idx] - tg[idx];
            mse_acc += e * e;
        }
        long long didx = ((long long)limit4 << 2) + gtid;
        if (didx < limit) {
            float d = in[didx] - in[didx + T];
            dif_acc += d * d;
        }
    }

    // ---- block reduction: wave-64 shuffle, then LDS across 4 waves ----
    #pragma unroll
    for (int off = 32; off > 0; off >>= 1) {
        mse_acc += __shfl_down(mse_acc, off, 64);
        dif_acc += __shfl_down(dif_acc, off, 64);
    }
    __shared__ float s_m[4], s_d[4];
    const int wave = threadIdx.x >> 6;
    if ((threadIdx.x & 63) == 0) { s_m[wave] = mse_acc; s_d[wave] = dif_acc; }
    __syncthreads();
    if (threadIdx.x == 0) {
        double m = (double)s_m[0] + (double)s_m[1] + (double)s_m[2] + (double)s_m[3];
        double d = (double)s_d[0] + (double)s_d[1] + (double)s_d[2] + (double)s_d[3];
        atomicAdd(&ws[0], m);
        atomicAdd(&ws[1], d);
    }
}

__global__ void cyclic_finalize_kernel(const double* __restrict__ ws,
                                       const int* __restrict__ pN,
                                       float* __restrict__ out,
                                       long long n)
{
    if (threadIdx.x == 0 && blockIdx.x == 0) {
        double mse = ws[0] / (double)n;
        double nom = (pN[0] != 1) ? (LAMDA * sqrt(ws[1])) : 0.0;
        out[0] = (float)(mse + nom);
    }
}

extern "C" void kernel_launch(void* const* d_in, const int* in_sizes, int n_in,
                              void* d_out, int out_size, void* d_ws, size_t ws_size,
                              hipStream_t stream) {
    const float* input  = (const float*)d_in[0];
    const float* target = (const float*)d_in[1];
    const int*   pT     = (const int*)d_in[2];
    const int*   pN     = (const int*)d_in[3];
    float* out = (float*)d_out;
    double* ws = (double*)d_ws;

    const long long n = (long long)in_sizes[0];

    // zero the two double accumulators (d_ws is poisoned 0xAA before every call)
    hipMemsetAsync(ws, 0, 2 * sizeof(double), stream);

    cyclic_reduce_kernel<<<GRID, BLOCK, 0, stream>>>(
        (const float4*)input, (const float4*)target, pT, pN, n, ws);

    cyclic_finalize_kernel<<<1, 64, 0, stream>>>(ws, pN, out, n);
}

// Round 6
// 150.088 us; speedup vs baseline: 3.4639x; 1.1738x over previous
//
#include <hip/hip_runtime.h>

// cyclicLoss: out = mean((input-target)^2) + 0.1*sqrt( sum_{i<(N-1)*T} (input[i]-input[i+T])^2 )
// fp32, n = N*T = 2048*8192 = 16.8M elements (64 MB each array).
//
// R5 = R4 (66us best) + two fixes:
//   - NO same-address double atomics (R4: 2x2048 serialized atomicAdds at one
//     L2 address = ~15-25us drain tail with waves retired -> 48% occupancy).
//     Blocks plain-store partials (contention-free); finalize dispatch reduces.
//     Also removes the memset dispatch (stores are unconditional).
//   - Unroll x4, 12 grouped loads (48 data VGPRs) -> forces allocator past
//     R4's VGPR=20, one wait round per 4 elements.

#define LAMDA 0.1
#define BLOCK 256
#define GRID 2048

__global__ __launch_bounds__(BLOCK, 4) void cyclic_reduce_kernel(
    const float4* __restrict__ in4,
    const float4* __restrict__ tg4,
    const int* __restrict__ pT,
    const int* __restrict__ pN,
    long long n,
    double* __restrict__ m_part,   // [GRID]
    double* __restrict__ d_part)   // [GRID]
{
    const int T = pT[0];
    const int N = pN[0];
    const int n4 = (int)(n >> 2);
    const int t4 = T >> 2;
    const long long limit = (N > 1) ? (long long)(N - 1) * (long long)T : 0;
    const int limit4 = (int)(limit >> 2);

    float mse_acc = 0.0f;
    float dif_acc = 0.0f;

    const int nth  = (int)gridDim.x * BLOCK;
    const int gtid = (int)blockIdx.x * BLOCK + (int)threadIdx.x;

    // ---- region 1: [0, limit4) — a, b, c all unconditional, unroll x4 ----
    int i = gtid;
    for (; i + 3 * nth < limit4; i += 4 * nth) {
        const int i1 = i + nth, i2 = i + 2 * nth, i3 = i + 3 * nth;

        // twelve loads, grouped, no branches / no uses between them
        float4 a0 = in4[i];        float4 c0 = in4[i + t4];
        float4 a1 = in4[i1];       float4 c1 = in4[i1 + t4];
        float4 a2 = in4[i2];       float4 c2 = in4[i2 + t4];
        float4 a3 = in4[i3];       float4 c3 = in4[i3 + t4];
        float4 b0 = tg4[i];        float4 b1 = tg4[i1];
        float4 b2 = tg4[i2];       float4 b3 = tg4[i3];

        float e0, e1, e2, e3, d0, d1, d2, d3;
        e0 = a0.x - b0.x; e1 = a0.y - b0.y; e2 = a0.z - b0.z; e3 = a0.w - b0.w;
        mse_acc += e0 * e0 + e1 * e1 + e2 * e2 + e3 * e3;
        d0 = a0.x - c0.x; d1 = a0.y - c0.y; d2 = a0.z - c0.z; d3 = a0.w - c0.w;
        dif_acc += d0 * d0 + d1 * d1 + d2 * d2 + d3 * d3;

        e0 = a1.x - b1.x; e1 = a1.y - b1.y; e2 = a1.z - b1.z; e3 = a1.w - b1.w;
        mse_acc += e0 * e0 + e1 * e1 + e2 * e2 + e3 * e3;
        d0 = a1.x - c1.x; d1 = a1.y - c1.y; d2 = a1.z - c1.z; d3 = a1.w - c1.w;
        dif_acc += d0 * d0 + d1 * d1 + d2 * d2 + d3 * d3;

        e0 = a2.x - b2.x; e1 = a2.y - b2.y; e2 = a2.z - b2.z; e3 = a2.w - b2.w;
        mse_acc += e0 * e0 + e1 * e1 + e2 * e2 + e3 * e3;
        d0 = a2.x - c2.x; d1 = a2.y - c2.y; d2 = a2.z - c2.z; d3 = a2.w - c2.w;
        dif_acc += d0 * d0 + d1 * d1 + d2 * d2 + d3 * d3;

        e0 = a3.x - b3.x; e1 = a3.y - b3.y; e2 = a3.z - b3.z; e3 = a3.w - b3.w;
        mse_acc += e0 * e0 + e1 * e1 + e2 * e2 + e3 * e3;
        d0 = a3.x - c3.x; d1 = a3.y - c3.y; d2 = a3.z - c3.z; d3 = a3.w - c3.w;
        dif_acc += d0 * d0 + d1 * d1 + d2 * d2 + d3 * d3;
    }
    for (; i < limit4; i += nth) {
        float4 a = in4[i];
        float4 c = in4[i + t4];
        float4 b = tg4[i];
        float e0 = a.x - b.x, e1 = a.y - b.y, e2 = a.z - b.z, e3 = a.w - b.w;
        mse_acc += e0 * e0 + e1 * e1 + e2 * e2 + e3 * e3;
        float d0 = a.x - c.x, d1 = a.y - c.y, d2 = a.z - c.z, d3 = a.w - c.w;
        dif_acc += d0 * d0 + d1 * d1 + d2 * d2 + d3 * d3;
    }

    // ---- region 2: [limit4, n4) — mse only ----
    for (int k = limit4 + gtid; k < n4; k += nth) {
        float4 a = in4[k];
        float4 b = tg4[k];
        float e0 = a.x - b.x, e1 = a.y - b.y, e2 = a.z - b.z, e3 = a.w - b.w;
        mse_acc += e0 * e0 + e1 * e1 + e2 * e2 + e3 * e3;
    }

    // ---- scalar tails (none for the bench shape; kept generic) ----
    {
        const float* in = (const float*)in4;
        const float* tg = (const float*)tg4;
        long long idx = ((long long)n4 << 2) + gtid;
        if (idx < n) {
            float e = in[idx] - tg[idx];
            mse_acc += e * e;
        }
        long long didx = ((long long)limit4 << 2) + gtid;
        if (didx < limit) {
            float d = in[didx] - in[didx + T];
            dif_acc += d * d;
        }
    }

    // ---- block reduction: wave-64 shuffle, then LDS across 4 waves ----
    #pragma unroll
    for (int off = 32; off > 0; off >>= 1) {
        mse_acc += __shfl_down(mse_acc, off, 64);
        dif_acc += __shfl_down(dif_acc, off, 64);
    }
    __shared__ float s_m[4], s_d[4];
    const int wave = threadIdx.x >> 6;
    if ((threadIdx.x & 63) == 0) { s_m[wave] = mse_acc; s_d[wave] = dif_acc; }
    __syncthreads();
    if (threadIdx.x == 0) {
        // plain stores — no contention, no atomic serialization tail
        m_part[blockIdx.x] = (double)s_m[0] + (double)s_m[1] + (double)s_m[2] + (double)s_m[3];
        d_part[blockIdx.x] = (double)s_d[0] + (double)s_d[1] + (double)s_d[2] + (double)s_d[3];
    }
}

#define FBLOCK 1024

__global__ __launch_bounds__(FBLOCK) void cyclic_finalize_kernel(
    const double* __restrict__ m_part,
    const double* __restrict__ d_part,
    const int* __restrict__ pN,
    float* __restrict__ out,
    long long n,
    int nparts)
{
    double m = 0.0, d = 0.0;
    for (int i = threadIdx.x; i < nparts; i += FBLOCK) {
        m += m_part[i];
        d += d_part[i];
    }
    #pragma unroll
    for (int off = 32; off > 0; off >>= 1) {
        m += __shfl_down(m, off, 64);
        d += __shfl_down(d, off, 64);
    }
    __shared__ double f_m[FBLOCK / 64], f_d[FBLOCK / 64];
    const int wave = threadIdx.x >> 6;
    if ((threadIdx.x & 63) == 0) { f_m[wave] = m; f_d[wave] = d; }
    __syncthreads();
    if (threadIdx.x == 0) {
        double mt = 0.0, dt = 0.0;
        #pragma unroll
        for (int w = 0; w < FBLOCK / 64; ++w) { mt += f_m[w]; dt += f_d[w]; }
        double mse = mt / (double)n;
        double nom = (pN[0] != 1) ? (LAMDA * sqrt(dt)) : 0.0;
        out[0] = (float)(mse + nom);
    }
}

extern "C" void kernel_launch(void* const* d_in, const int* in_sizes, int n_in,
                              void* d_out, int out_size, void* d_ws, size_t ws_size,
                              hipStream_t stream) {
    const float* input  = (const float*)d_in[0];
    const float* target = (const float*)d_in[1];
    const int*   pT     = (const int*)d_in[2];
    const int*   pN     = (const int*)d_in[3];
    float* out = (float*)d_out;

    const long long n = (long long)in_sizes[0];

    double* m_part = (double*)d_ws;
    double* d_part = m_part + GRID;

    // every block writes its partial unconditionally -> no memset needed
    cyclic_reduce_kernel<<<GRID, BLOCK, 0, stream>>>(
        (const float4*)input, (const float4*)target, pT, pN, n, m_part, d_part);

    cyclic_finalize_kernel<<<1, FBLOCK, 0, stream>>>(m_part, d_part, pN, out, n, GRID);
}

// Round 7
// 150.000 us; speedup vs baseline: 3.4660x; 1.0006x over previous
//
#include <hip/hip_runtime.h>

// cyclicLoss: out = mean((input-target)^2) + 0.1*sqrt( sum_{i<(N-1)*T} (input[i]-input[i+T])^2 )
// fp32, n = N*T = 2048*8192 = 16.8M elements (64 MB each array).
//
// R6 = R5 (45us) + row-walk tiling to cut LOGICAL traffic 192->136 MB:
//   - Evidence: R4->R5 halved wait-rounds but only gave 1.47x; throughput
//     plateaus near ~66 outstanding lines/CU -> line-transit (MSHR) capped.
//     So reduce lines: block owns an 8-row x 256-float4 tile, loads 9 input
//     rows (1 overlap) + 8 target rows; input is read 1.125x instead of 2x.
//   - All 17 loads/thread independent, straight-line, unconditional
//     (last-segment 9th row handled by wave-uniform clamp + cndmask zero).
//   - No fence/ticket (R1-R3 lesson), plain-store partials (R5 lesson),
//     separate tiny finalize dispatch.
//   - Generic fallback path (R5's flat loop) if the shape doesn't decompose;
//     bench shape (T=8192,N=2048) always takes the fast path.

#define LAMDA 0.1
#define BLOCK 256
#define GRID 2048
#define RSEG 8

__global__ __launch_bounds__(BLOCK, 4) void cyclic_reduce_kernel(
    const float4* __restrict__ in4,
    const float4* __restrict__ tg4,
    const int* __restrict__ pT,
    const int* __restrict__ pN,
    long long n,
    double* __restrict__ m_part,   // [GRID]
    double* __restrict__ d_part)   // [GRID]
{
    const int T = pT[0];
    const int N = pN[0];
    const int n4 = (int)(n >> 2);
    const int t4 = T >> 2;
    const long long limit = (N > 1) ? (long long)(N - 1) * (long long)T : 0;
    const int limit4 = (int)(limit >> 2);

    float mse_acc = 0.0f;
    float dif_acc = 0.0f;

    // ---- fast-path shape check (wave-uniform scalar) ----
    const int colchunks = (T % 4 == 0) ? (t4 / BLOCK) : 0;
    bool fast = (colchunks > 0) && (t4 % BLOCK == 0)
             && ((long long)N * (long long)T == n)
             && ((int)gridDim.x % colchunks == 0);
    int rowsegs = 0;
    if (fast) {
        rowsegs = (int)gridDim.x / colchunks;
        fast = (rowsegs > 0) && (N % rowsegs == 0) && (N / rowsegs == RSEG);
    }

    if (fast) {
        const int seg      = (int)blockIdx.x;
        const int colchunk = seg % colchunks;
        const int rowseg   = seg / colchunks;
        const int row0     = rowseg * RSEG;
        const int col4     = colchunk * BLOCK + (int)threadIdx.x;
        const float4* px = in4 + (long long)row0 * t4 + col4;
        const float4* pt = tg4 + (long long)row0 * t4 + col4;

        // 9th input row: clamped for the last segment (wave-uniform)
        const bool has9 = (row0 + RSEG < N);
        const int  ofs9 = has9 ? RSEG * t4 : (RSEG - 1) * t4;

        float4 x[RSEG + 1];
        float4 b[RSEG];
        #pragma unroll
        for (int k = 0; k < RSEG; ++k) x[k] = px[k * t4];
        x[RSEG] = px[ofs9];
        #pragma unroll
        for (int k = 0; k < RSEG; ++k) b[k] = pt[k * t4];

        #pragma unroll
        for (int k = 0; k < RSEG; ++k) {
            float e0 = x[k].x - b[k].x, e1 = x[k].y - b[k].y;
            float e2 = x[k].z - b[k].z, e3 = x[k].w - b[k].w;
            mse_acc += e0 * e0 + e1 * e1 + e2 * e2 + e3 * e3;
        }
        #pragma unroll
        for (int k = 0; k < RSEG - 1; ++k) {
            float d0 = x[k].x - x[k + 1].x, d1 = x[k].y - x[k + 1].y;
            float d2 = x[k].z - x[k + 1].z, d3 = x[k].w - x[k + 1].w;
            dif_acc += d0 * d0 + d1 * d1 + d2 * d2 + d3 * d3;
        }
        {
            float d0 = x[RSEG - 1].x - x[RSEG].x, d1 = x[RSEG - 1].y - x[RSEG].y;
            float d2 = x[RSEG - 1].z - x[RSEG].z, d3 = x[RSEG - 1].w - x[RSEG].w;
            float dd = d0 * d0 + d1 * d1 + d2 * d2 + d3 * d3;
            dif_acc += has9 ? dd : 0.0f;
        }
    } else {
        // ---- generic fallback: R5's flat region-split loops ----
        const int nth  = (int)gridDim.x * BLOCK;
        const int gtid = (int)blockIdx.x * BLOCK + (int)threadIdx.x;

        int i = gtid;
        for (; i + 3 * nth < limit4; i += 4 * nth) {
            const int i1 = i + nth, i2 = i + 2 * nth, i3 = i + 3 * nth;
            float4 a0 = in4[i];        float4 c0 = in4[i + t4];
            float4 a1 = in4[i1];       float4 c1 = in4[i1 + t4];
            float4 a2 = in4[i2];       float4 c2 = in4[i2 + t4];
            float4 a3 = in4[i3];       float4 c3 = in4[i3 + t4];
            float4 b0 = tg4[i];        float4 b1 = tg4[i1];
            float4 b2 = tg4[i2];       float4 b3 = tg4[i3];

            float e0, e1, e2, e3, d0, d1, d2, d3;
            e0 = a0.x - b0.x; e1 = a0.y - b0.y; e2 = a0.z - b0.z; e3 = a0.w - b0.w;
            mse_acc += e0 * e0 + e1 * e1 + e2 * e2 + e3 * e3;
            d0 = a0.x - c0.x; d1 = a0.y - c0.y; d2 = a0.z - c0.z; d3 = a0.w - c0.w;
            dif_acc += d0 * d0 + d1 * d1 + d2 * d2 + d3 * d3;
            e0 = a1.x - b1.x; e1 = a1.y - b1.y; e2 = a1.z - b1.z; e3 = a1.w - b1.w;
            mse_acc += e0 * e0 + e1 * e1 + e2 * e2 + e3 * e3;
            d0 = a1.x - c1.x; d1 = a1.y - c1.y; d2 = a1.z - c1.z; d3 = a1.w - c1.w;
            dif_acc += d0 * d0 + d1 * d1 + d2 * d2 + d3 * d3;
            e0 = a2.x - b2.x; e1 = a2.y - b2.y; e2 = a2.z - b2.z; e3 = a2.w - b2.w;
            mse_acc += e0 * e0 + e1 * e1 + e2 * e2 + e3 * e3;
            d0 = a2.x - c2.x; d1 = a2.y - c2.y; d2 = a2.z - c2.z; d3 = a2.w - c2.w;
            dif_acc += d0 * d0 + d1 * d1 + d2 * d2 + d3 * d3;
            e0 = a3.x - b3.x; e1 = a3.y - b3.y; e2 = a3.z - b3.z; e3 = a3.w - b3.w;
            mse_acc += e0 * e0 + e1 * e1 + e2 * e2 + e3 * e3;
            d0 = a3.x - c3.x; d1 = a3.y - c3.y; d2 = a3.z - c3.z; d3 = a3.w - c3.w;
            dif_acc += d0 * d0 + d1 * d1 + d2 * d2 + d3 * d3;
        }
        for (; i < limit4; i += nth) {
            float4 a = in4[i];
            float4 c = in4[i + t4];
            float4 b = tg4[i];
            float e0 = a.x - b.x, e1 = a.y - b.y, e2 = a.z - b.z, e3 = a.w - b.w;
            mse_acc += e0 * e0 + e1 * e1 + e2 * e2 + e3 * e3;
            float d0 = a.x - c.x, d1 = a.y - c.y, d2 = a.z - c.z, d3 = a.w - c.w;
            dif_acc += d0 * d0 + d1 * d1 + d2 * d2 + d3 * d3;
        }
        for (int k = limit4 + gtid; k < n4; k += nth) {
            float4 a = in4[k];
            float4 b = tg4[k];
            float e0 = a.x - b.x, e1 = a.y - b.y, e2 = a.z - b.z, e3 = a.w - b.w;
            mse_acc += e0 * e0 + e1 * e1 + e2 * e2 + e3 * e3;
        }
        {
            const float* in = (const float*)in4;
            const float* tg = (const float*)tg4;
            long long idx = ((long long)n4 << 2) + gtid;
            if (idx < n) {
                float e = in[idx] - tg[idx];
                mse_acc += e * e;
            }
            long long didx = ((long long)limit4 << 2) + gtid;
            if (didx < limit) {
                float d = in[didx] - in[didx + T];
                dif_acc += d * d;
            }
        }
    }

    // ---- block reduction: wave-64 shuffle, then LDS across 4 waves ----
    #pragma unroll
    for (int off = 32; off > 0; off >>= 1) {
        mse_acc += __shfl_down(mse_acc, off, 64);
        dif_acc += __shfl_down(dif_acc, off, 64);
    }
    __shared__ float s_m[4], s_d[4];
    const int wave = threadIdx.x >> 6;
    if ((threadIdx.x & 63) == 0) { s_m[wave] = mse_acc; s_d[wave] = dif_acc; }
    __syncthreads();
    if (threadIdx.x == 0) {
        m_part[blockIdx.x] = (double)s_m[0] + (double)s_m[1] + (double)s_m[2] + (double)s_m[3];
        d_part[blockIdx.x] = (double)s_d[0] + (double)s_d[1] + (double)s_d[2] + (double)s_d[3];
    }
}

#define FBLOCK 1024

__global__ __launch_bounds__(FBLOCK) void cyclic_finalize_kernel(
    const double* __restrict__ m_part,
    const double* __restrict__ d_part,
    const int* __restrict__ pN,
    float* __restrict__ out,
    long long n,
    int nparts)
{
    double m = 0.0, d = 0.0;
    for (int i = threadIdx.x; i < nparts; i += FBLOCK) {
        m += m_part[i];
        d += d_part[i];
    }
    #pragma unroll
    for (int off = 32; off > 0; off >>= 1) {
        m += __shfl_down(m, off, 64);
        d += __shfl_down(d, off, 64);
    }
    __shared__ double f_m[FBLOCK / 64], f_d[FBLOCK / 64];
    const int wave = threadIdx.x >> 6;
    if ((threadIdx.x & 63) == 0) { f_m[wave] = m; f_d[wave] = d; }
    __syncthreads();
    if (threadIdx.x == 0) {
        double mt = 0.0, dt = 0.0;
        #pragma unroll
        for (int w = 0; w < FBLOCK / 64; ++w) { mt += f_m[w]; dt += f_d[w]; }
        double mse = mt / (double)n;
        double nom = (pN[0] != 1) ? (LAMDA * sqrt(dt)) : 0.0;
        out[0] = (float)(mse + nom);
    }
}

extern "C" void kernel_launch(void* const* d_in, const int* in_sizes, int n_in,
                              void* d_out, int out_size, void* d_ws, size_t ws_size,
                              hipStream_t stream) {
    const float* input  = (const float*)d_in[0];
    const float* target = (const float*)d_in[1];
    const int*   pT     = (const int*)d_in[2];
    const int*   pN     = (const int*)d_in[3];
    float* out = (float*)d_out;

    const long long n = (long long)in_sizes[0];

    double* m_part = (double*)d_ws;
    double* d_part = m_part + GRID;

    cyclic_reduce_kernel<<<GRID, BLOCK, 0, stream>>>(
        (const float4*)input, (const float4*)target, pT, pN, n, m_part, d_part);

    cyclic_finalize_kernel<<<1, FBLOCK, 0, stream>>>(m_part, d_part, pN, out, n, GRID);
}